// Round 5
// baseline (2627.407 us; speedup 1.0000x reference)
//
#include <hip/hip_runtime.h>
#include <cstddef>

#define BB    16
#define NN    2048
#define TPB   256
#define SPLIT 64                 // row/col slices per batch == blocks per group
#define TILE  32                 // NN / SPLIT
#define GRID  (BB * SPLIT)       // 1024 blocks = 4/CU at launch_bounds(256,4)
#define NPAIR 4                  // 8 cols/rows per thread as 4 float2 pairs
#define EPSF  1e-9f
#define CTRPAD 32                // one counter per 128B to avoid line contention
#define PIDX(s,b,i) ((((size_t)(s)) * BB + (b)) * NN + (i))

typedef float f2 __attribute__((ext_vector_type(2)));

__device__ __forceinline__ float fast_exp2(float x) {
#if __has_builtin(__builtin_amdgcn_exp2f)
    return __builtin_amdgcn_exp2f(x);
#else
    return exp2f(x);
#endif
}

__device__ __forceinline__ void backoff() {
#if __has_builtin(__builtin_amdgcn_s_sleep)
    __builtin_amdgcn_s_sleep(8);
#endif
}

// use-once group barrier: 64 arrivals, device-scope, bounded spin (no hang).
__device__ __forceinline__ void group_barrier(int* c) {
    __syncthreads();
    if (threadIdx.x == 0) {
        __threadfence();                                      // release writes
        __hip_atomic_fetch_add(c, 1, __ATOMIC_RELEASE, __HIP_MEMORY_SCOPE_AGENT);
        int spins = 0;
        while (__hip_atomic_load(c, __ATOMIC_ACQUIRE, __HIP_MEMORY_SCOPE_AGENT) < SPLIT) {
            backoff();
            if (++spins > (1 << 21)) break;                   // ~0.5s safety valve
        }
        __threadfence();                                      // acquire/invalidate
    }
    __syncthreads();
}

__global__ __launch_bounds__(TPB, 4) void emd_all(
    const float* __restrict__ preds, const float* __restrict__ labels,
    float* __restrict__ Sp, float* __restrict__ Tp,
    float* __restrict__ RSp, float* __restrict__ RRp,
    int* __restrict__ ctr, float* __restrict__ out)
{
    __shared__ float4 s_P[TILE], s_L[TILE];      // rows/cols: x,y,z, c1*norm (per round)
    __shared__ float  s_pn[TILE], s_ln[TILE];    // raw norms
    __shared__ float  s_cur[TILE], s_cost[TILE], s_cc[TILE];   // persistent state
    __shared__ float  s_ws[2][8][TILE];          // partial-reduction scratch

    const int blk = blockIdx.x;
    const int split = blk & (SPLIT - 1);
    const int b = blk >> 6;
    const int t = threadIdx.x;
    const int base = b * NN;
    const int r = t & (TILE - 1);
    const int g = t >> 5;                        // 0..7
    const int row0 = split * TILE;

    if (t < TILE) {
        int i = base + row0 + t;
        const float* p = preds + (size_t)i * 3;
        float x = p[0], y = p[1], z = p[2];
        s_P[t] = make_float4(x, y, z, 0.f);
        s_pn[t] = x * x + y * y + z * z;
        const float* l = labels + (size_t)i * 3;
        float a = l[0], c = l[1], d = l[2];
        s_L[t] = make_float4(a, c, d, 0.f);
        s_ln[t] = a * a + c * c + d * d;
        s_cur[t] = 1.f;                          // persists across all rounds
        s_cost[t] = 1.f;
    }

    const float LOG2E = 1.44269504088896f;
    for (int k = 0; k < 10; k++) {
        const float ef = (k < 8) ? -(float)(1 << (14 - 2 * k)) : ((k == 8) ? -0.25f : 0.f);
        const float c1 = ef * LOG2E;
        const float invc1 = (k < 9) ? 1.f / c1 : 0.f;
        const float n2c1 = -2.f * c1;

        // ================= phase A: col sums S,T =================
        if (k > 0) {                             // combB(k-1): reduce row partials
            float aRS = 0.f, aRR = 0.f;
#pragma unroll
            for (int q = 0; q < SPLIT / 8; q++) {
                size_t off = PIDX(g * (SPLIT / 8) + q, b, row0 + r);
                aRS += RSp[off];
                aRR += RRp[off];
            }
            s_ws[0][g][r] = aRS;
            s_ws[1][g][r] = aRR;
        }
        __syncthreads();
        float cb = 0.f;
        if (t < TILE) {
            if (k > 0) {
                float rs = 0.f, rr = 0.f;
#pragma unroll
                for (int q = 0; q < 8; q++) { rs += s_ws[0][q][t]; rr += s_ws[1][q][t]; }
                float cu = s_cur[t];
                cb = cu * rr;                              // round k-1 result term
                s_cur[t] = fmaxf(cu * (1.f - rs), 0.f);
            }
            s_P[t].w = c1 * s_pn[t];
        }
        if (k > 0 && t < 64) {
#pragma unroll
            for (int o = 32; o > 0; o >>= 1) cb += __shfl_down(cb, o, 64);
            if (t == 0) atomicAdd(out, cb);
        }

        f2 gx[NPAIR], gy[NPAIR], gz[NPAIR], am[NPAIR], Sa[NPAIR], Ta[NPAIR];
#pragma unroll
        for (int p = 0; p < NPAIR; p++) {
            int m0 = t + (2 * p) * TPB, m1 = t + (2 * p + 1) * TPB;
            const float* l0 = labels + (size_t)(base + m0) * 3;
            const float* l1 = labels + (size_t)(base + m1) * 3;
            float ax = l0[0], ay = l0[1], az = l0[2];
            float bx = l1[0], by = l1[1], bz = l1[2];
            gx[p] = (f2){n2c1 * ax, n2c1 * bx};
            gy[p] = (f2){n2c1 * ay, n2c1 * by};
            gz[p] = (f2){n2c1 * az, n2c1 * bz};
            am[p] = (f2){c1 * (ax * ax + ay * ay + az * az),
                         c1 * (bx * bx + by * by + bz * bz)};
            Sa[p] = (f2){0.f, 0.f};
            Ta[p] = (f2){0.f, 0.f};
        }
        __syncthreads();

#pragma unroll 4
        for (int j = 0; j < TILE; j++) {
            float4 P = s_P[j];
            float cu = s_cur[j];
#pragma unroll
            for (int p = 0; p < NPAIR; p++) {
                f2 arg = P.x * gx[p] + (P.y * gy[p] + (P.z * gz[p] + (am[p] + P.w)));
                f2 e; e.x = fast_exp2(arg.x); e.y = fast_exp2(arg.y);
                Sa[p] += e;
                Ta[p] += e * cu;
            }
        }
#pragma unroll
        for (int p = 0; p < NPAIR; p++) {
            int m0 = t + (2 * p) * TPB, m1 = t + (2 * p + 1) * TPB;
            Sp[PIDX(split, b, m0)] = Sa[p].x;
            Sp[PIDX(split, b, m1)] = Sa[p].y;
            Tp[PIDX(split, b, m0)] = Ta[p].x;
            Tp[PIDX(split, b, m1)] = Ta[p].y;
        }
        group_barrier(ctr + (size_t)(2 * k * BB + b) * CTRPAD);

        // ================= phase B: row sums RS,RR =================
        {
            float aS = 0.f, aT = 0.f;
#pragma unroll
            for (int q = 0; q < SPLIT / 8; q++) {
                size_t off = PIDX(g * (SPLIT / 8) + q, b, row0 + r);
                aS += Sp[off];
                aT += Tp[off];
            }
            s_ws[0][g][r] = aS;
            s_ws[1][g][r] = aT;
        }
        __syncthreads();
        if (t < TILE) {                          // combA: per-col scalars
            float S = 0.f, T = 0.f;
#pragma unroll
            for (int q = 0; q < 8; q++) { S += s_ws[0][q][t]; T += s_ws[1][q][t]; }
            float cost = s_cost[t];
            float D1 = fmaf(cost, S, EPSF);
            float S2 = cost * T / D1;
            float bw = fminf(cost / (S2 + EPSF), 1.f);
            s_cc[t] = cost * bw / D1;
            s_cost[t] = fmaxf(fmaf(-S2, bw, cost), 0.f);
            s_L[t].w = c1 * s_ln[t];
        }

        f2 hx[NPAIR], hy[NPAIR], hz[NPAIR], hn[NPAIR], RSa[NPAIR], RRa[NPAIR];
        const float fx = (k == 9) ? 1.f : n2c1;
#pragma unroll
        for (int p = 0; p < NPAIR; p++) {
            int n0 = t + (2 * p) * TPB, n1 = t + (2 * p + 1) * TPB;
            const float* p0 = preds + (size_t)(base + n0) * 3;
            const float* p1 = preds + (size_t)(base + n1) * 3;
            float ax = p0[0], ay = p0[1], az = p0[2];
            float bx = p1[0], by = p1[1], bz = p1[2];
            hx[p] = (f2){fx * ax, fx * bx};
            hy[p] = (f2){fx * ay, fx * by};
            hz[p] = (f2){fx * az, fx * bz};
            float na = ax * ax + ay * ay + az * az;
            float nb = bx * bx + by * by + bz * bz;
            hn[p] = (k == 9) ? (f2){na, nb} : (f2){c1 * na, c1 * nb};
            RSa[p] = (f2){0.f, 0.f};
            RRa[p] = (f2){0.f, 0.f};
        }
        __syncthreads();

        if (k < 9) {
#pragma unroll 4
            for (int j = 0; j < TILE; j++) {
                float4 L = s_L[j];
                float ccj = s_cc[j];
#pragma unroll
                for (int p = 0; p < NPAIR; p++) {
                    f2 arg = L.x * hx[p] + (L.y * hy[p] + (L.z * hz[p] + (hn[p] + L.w)));
                    f2 e; e.x = fast_exp2(arg.x); e.y = fast_exp2(arg.y);
                    f2 w = e * ccj;
                    RSa[p] += w;
                    RRa[p] += w * arg;           // sum w*arg; *1/c1 at store
                }
            }
#pragma unroll
            for (int p = 0; p < NPAIR; p++) {
                int n0 = t + (2 * p) * TPB, n1 = t + (2 * p + 1) * TPB;
                RSp[PIDX(split, b, n0)] = RSa[p].x;
                RSp[PIDX(split, b, n1)] = RSa[p].y;
                RRp[PIDX(split, b, n0)] = RRa[p].x * invc1;
                RRp[PIDX(split, b, n1)] = RRa[p].y * invc1;
            }
        } else {                                 // ef=0: e==1, w=cc, need raw pw
#pragma unroll 4
            for (int j = 0; j < TILE; j++) {
                float4 L = s_L[j];
                float ccj = s_cc[j];
                float lnj = s_ln[j];
#pragma unroll
                for (int p = 0; p < NPAIR; p++) {
                    f2 dot = L.x * hx[p] + (L.y * hy[p] + L.z * hz[p]);
                    f2 pw = (hn[p] + lnj) - 2.f * dot;
                    RRa[p] += ccj * pw;
                }
            }
#pragma unroll
            for (int p = 0; p < NPAIR; p++) {
                int n0 = t + (2 * p) * TPB, n1 = t + (2 * p + 1) * TPB;
                RRp[PIDX(split, b, n0)] = RRa[p].x;
                RRp[PIDX(split, b, n1)] = RRa[p].y;
            }
        }
        group_barrier(ctr + (size_t)((2 * k + 1) * BB + b) * CTRPAD);
    }

    // ============ final: out += sum_n cur9[n] * rr9[n] ============
    {
        float aRR = 0.f;
#pragma unroll
        for (int q = 0; q < SPLIT / 8; q++)
            aRR += RRp[PIDX(g * (SPLIT / 8) + q, b, row0 + r)];
        s_ws[0][g][r] = aRR;
    }
    __syncthreads();
    float cb = 0.f;
    if (t < TILE) {
        float rr = 0.f;
#pragma unroll
        for (int q = 0; q < 8; q++) rr += s_ws[0][q][t];
        cb = s_cur[t] * rr;
    }
    if (t < 64) {
#pragma unroll
        for (int o = 32; o > 0; o >>= 1) cb += __shfl_down(cb, o, 64);
        if (t == 0) atomicAdd(out, cb);
    }
}

extern "C" void kernel_launch(void* const* d_in, const int* in_sizes, int n_in,
                              void* d_out, int out_size, void* d_ws, size_t ws_size,
                              hipStream_t stream) {
    const float* preds  = (const float*)d_in[0];
    const float* labels = (const float*)d_in[1];
    float* out = (float*)d_out;
    float* ws  = (float*)d_ws;

    const size_t P = (size_t)SPLIT * BB * NN;    // 2M floats per partial array
    float* Sp  = ws;
    float* Tp  = ws + P;
    float* RSp = ws + 2 * P;
    float* RRp = ws + 3 * P;
    int*   ctr = (int*)(ws + 4 * P);             // 20 phases x 16 groups, padded
    // total ws use: 32 MB + 40 KB

    hipMemsetAsync(d_out, 0, sizeof(float), stream);
    hipMemsetAsync(ctr, 0, (size_t)20 * BB * CTRPAD * sizeof(int), stream);
    emd_all<<<GRID, TPB, 0, stream>>>(preds, labels, Sp, Tp, RSp, RRp, ctr, out);
}

// Round 6
// 475.570 us; speedup vs baseline: 5.5248x; 5.5248x over previous
//
#include <hip/hip_runtime.h>
#include <cstddef>

#define BB    16
#define NN    2048
#define BN    (BB * NN)
#define TPB   256
#define SPLIT 64                 // slices per batch; grid = BB*SPLIT = 1024 = 4/CU
#define TILE  32                 // NN / SPLIT rows (cols) staged per block
#define NPAIR 4                  // 8 cols/rows per thread as 4 float2 pairs
#define EPSF  1e-9f
#define PIDX(s,b,i) ((((size_t)(s)) * BB + (b)) * NN + (i))

typedef float f2 __attribute__((ext_vector_type(2)));

__device__ __forceinline__ float fast_exp2(float x) {
#if __has_builtin(__builtin_amdgcn_exp2f)
    return __builtin_amdgcn_exp2f(x);
#else
    return exp2f(x);
#endif
}

// passA(k): fused combB(k-1) + column sums S,T of round k.
__global__ __launch_bounds__(TPB, 4) void passA(
    const float* __restrict__ preds, const float* __restrict__ labels,
    const float* __restrict__ curprev, float* __restrict__ curout,
    const float* __restrict__ RSp, const float* __restrict__ RRp,
    float* __restrict__ Sp, float* __restrict__ Tp,
    float* __restrict__ out, float c1, int k)
{
    __shared__ float4 s_P[TILE];
    __shared__ float  s_cu[TILE];
    __shared__ float  s_ws[2][8][TILE];
    const int blk = blockIdx.x;
    const int split = blk & (SPLIT - 1), b = blk >> 6;
    const int t = threadIdx.x;
    const int base = b * NN;
    const int r = t & (TILE - 1), g = t >> 5;   // 8 groups x 32 threads
    const int row0 = split * TILE;

    if (k > 0) {                 // reduce prev round's row partials (64 slices)
        float aRS = 0.f, aRR = 0.f;
#pragma unroll
        for (int q = 0; q < 8; q++) {
            size_t off = PIDX(g * 8 + q, b, row0 + r);
            aRS += RSp[off];
            aRR += RRp[off];
        }
        s_ws[0][g][r] = aRS;
        s_ws[1][g][r] = aRR;
    }
    __syncthreads();

    float cb = 0.f;
    if (t < TILE) {
        int idx = base + row0 + t;
        const float* p = preds + (size_t)idx * 3;
        float x = p[0], y = p[1], z = p[2];
        float cu;
        if (k == 0) cu = 1.f;
        else {
            float rs = 0.f, rr = 0.f;
#pragma unroll
            for (int q = 0; q < 8; q++) { rs += s_ws[0][q][t]; rr += s_ws[1][q][t]; }
            float cup = curprev[idx];
            cb = cup * rr;                      // round k-1 result term
            cu = fmaxf(cup * (1.f - rs), 0.f);
        }
        s_P[t] = make_float4(x, y, z, c1 * (x * x + y * y + z * z));
        s_cu[t] = cu;
        curout[idx] = cu;
    }
    if (k > 0 && t < 64) {
#pragma unroll
        for (int o = 32; o > 0; o >>= 1) cb += __shfl_down(cb, o, 64);
        if (t == 0) atomicAdd(out, cb);
    }

    // register-held label columns, prescaled
    f2 gx[NPAIR], gy[NPAIR], gz[NPAIR], am[NPAIR], Sa[NPAIR], Ta[NPAIR];
    const float n2c1 = -2.f * c1;
#pragma unroll
    for (int p = 0; p < NPAIR; p++) {
        int m0 = t + (2 * p) * TPB, m1 = t + (2 * p + 1) * TPB;
        const float* l0 = labels + (size_t)(base + m0) * 3;
        const float* l1 = labels + (size_t)(base + m1) * 3;
        float ax = l0[0], ay = l0[1], az = l0[2];
        float bx = l1[0], by = l1[1], bz = l1[2];
        gx[p] = (f2){n2c1 * ax, n2c1 * bx};
        gy[p] = (f2){n2c1 * ay, n2c1 * by};
        gz[p] = (f2){n2c1 * az, n2c1 * bz};
        am[p] = (f2){c1 * (ax * ax + ay * ay + az * az),
                     c1 * (bx * bx + by * by + bz * bz)};
        Sa[p] = (f2){0.f, 0.f};
        Ta[p] = (f2){0.f, 0.f};
    }
    __syncthreads();

#pragma unroll 4
    for (int j = 0; j < TILE; j++) {
        float4 P = s_P[j];
        float cu = s_cu[j];
#pragma unroll
        for (int p = 0; p < NPAIR; p++) {
            f2 arg = P.x * gx[p] + (P.y * gy[p] + (P.z * gz[p] + (am[p] + P.w)));
            f2 e; e.x = fast_exp2(arg.x); e.y = fast_exp2(arg.y);
            Sa[p] += e;
            Ta[p] += e * cu;
        }
    }
#pragma unroll
    for (int p = 0; p < NPAIR; p++) {
        int m0 = t + (2 * p) * TPB, m1 = t + (2 * p + 1) * TPB;
        Sp[PIDX(split, b, m0)] = Sa[p].x;
        Sp[PIDX(split, b, m1)] = Sa[p].y;
        Tp[PIDX(split, b, m0)] = Ta[p].x;
        Tp[PIDX(split, b, m1)] = Ta[p].y;
    }
}

// passB(k): fused combA(k) + row sums RS,RR of round k.
__global__ __launch_bounds__(TPB, 4) void passB(
    const float* __restrict__ preds, const float* __restrict__ labels,
    const float* __restrict__ Sp, const float* __restrict__ Tp,
    const float* __restrict__ costprev, float* __restrict__ costout,
    float* __restrict__ RSp, float* __restrict__ RRp,
    float c1, float invc1, int k, int last)
{
    __shared__ float4 s_L[TILE];
    __shared__ float  s_cc[TILE];
    __shared__ float  s_ws[2][8][TILE];
    const int blk = blockIdx.x;
    const int split = blk & (SPLIT - 1), b = blk >> 6;
    const int t = threadIdx.x;
    const int base = b * NN;
    const int r = t & (TILE - 1), g = t >> 5;
    const int row0 = split * TILE;

    {                            // reduce this round's column partials
        float aS = 0.f, aT = 0.f;
#pragma unroll
        for (int q = 0; q < 8; q++) {
            size_t off = PIDX(g * 8 + q, b, row0 + r);
            aS += Sp[off];
            aT += Tp[off];
        }
        s_ws[0][g][r] = aS;
        s_ws[1][g][r] = aT;
    }
    __syncthreads();

    if (t < TILE) {              // combA: per-column scalars
        int idx = base + row0 + t;
        const float* l = labels + (size_t)idx * 3;
        float lx = l[0], ly = l[1], lz = l[2];
        float lm2 = lx * lx + ly * ly + lz * lz;
        float S = 0.f, T = 0.f;
#pragma unroll
        for (int q = 0; q < 8; q++) { S += s_ws[0][q][t]; T += s_ws[1][q][t]; }
        float cost = (k == 0) ? 1.f : costprev[idx];
        float D1 = fmaf(cost, S, EPSF);
        float S2 = cost * T / D1;
        float bw = fminf(cost / (S2 + EPSF), 1.f);
        s_cc[t] = cost * bw / D1;
        costout[idx] = fmaxf(fmaf(-S2, bw, cost), 0.f);
        s_L[t] = make_float4(lx, ly, lz, last ? lm2 : c1 * lm2);
    }

    // register-held pred rows (prescaled by -2*c1 except last round)
    f2 hx[NPAIR], hy[NPAIR], hz[NPAIR], hn[NPAIR], RSa[NPAIR], RRa[NPAIR];
    const float fx = last ? 1.f : -2.f * c1;
#pragma unroll
    for (int p = 0; p < NPAIR; p++) {
        int n0 = t + (2 * p) * TPB, n1 = t + (2 * p + 1) * TPB;
        const float* p0 = preds + (size_t)(base + n0) * 3;
        const float* p1 = preds + (size_t)(base + n1) * 3;
        float ax = p0[0], ay = p0[1], az = p0[2];
        float bx = p1[0], by = p1[1], bz = p1[2];
        hx[p] = (f2){fx * ax, fx * bx};
        hy[p] = (f2){fx * ay, fx * by};
        hz[p] = (f2){fx * az, fx * bz};
        float na = ax * ax + ay * ay + az * az;
        float nb = bx * bx + by * by + bz * bz;
        hn[p] = last ? (f2){na, nb} : (f2){c1 * na, c1 * nb};
        RSa[p] = (f2){0.f, 0.f};
        RRa[p] = (f2){0.f, 0.f};
    }
    __syncthreads();

    if (!last) {
#pragma unroll 4
        for (int j = 0; j < TILE; j++) {
            float4 L = s_L[j];
            float ccj = s_cc[j];
#pragma unroll
            for (int p = 0; p < NPAIR; p++) {
                f2 arg = L.x * hx[p] + (L.y * hy[p] + (L.z * hz[p] + (hn[p] + L.w)));
                f2 e; e.x = fast_exp2(arg.x); e.y = fast_exp2(arg.y);
                f2 w = e * ccj;
                RSa[p] += w;
                RRa[p] += w * arg;            // sum w*arg; *1/c1 at store
            }
        }
#pragma unroll
        for (int p = 0; p < NPAIR; p++) {
            int n0 = t + (2 * p) * TPB, n1 = t + (2 * p + 1) * TPB;
            RSp[PIDX(split, b, n0)] = RSa[p].x;
            RSp[PIDX(split, b, n1)] = RSa[p].y;
            RRp[PIDX(split, b, n0)] = RRa[p].x * invc1;
            RRp[PIDX(split, b, n1)] = RRa[p].y * invc1;
        }
    } else {                                  // ef = 0: e == 1, need raw pw
#pragma unroll 4
        for (int j = 0; j < TILE; j++) {
            float4 L = s_L[j];
            float ccj = s_cc[j];
#pragma unroll
            for (int p = 0; p < NPAIR; p++) {
                f2 dot = L.x * hx[p] + (L.y * hy[p] + L.z * hz[p]);
                f2 pw = (hn[p] + L.w) - 2.f * dot;
                RRa[p] += ccj * pw;
            }
        }
#pragma unroll
        for (int p = 0; p < NPAIR; p++) {
            int n0 = t + (2 * p) * TPB, n1 = t + (2 * p + 1) * TPB;
            RRp[PIDX(split, b, n0)] = RRa[p].x;
            RRp[PIDX(split, b, n1)] = RRa[p].y;
        }
    }
}

// out += sum_n cur9[n] * (sum_s RRp[s][n])
__global__ __launch_bounds__(TPB) void finalK(const float* __restrict__ cur,
                                              const float* __restrict__ RRp,
                                              float* __restrict__ out)
{
    int t = threadIdx.x;
    int i = blockIdx.x * TPB + t;
    int b = i >> 11, n = i & (NN - 1);
    float acc = 0.f;
#pragma unroll 8
    for (int s = 0; s < SPLIT; s++) acc += RRp[PIDX(s, b, n)];
    float cb = cur[i] * acc;
#pragma unroll
    for (int o = 32; o > 0; o >>= 1) cb += __shfl_down(cb, o, 64);
    __shared__ float s_red[TPB / 64];
    if ((t & 63) == 0) s_red[t >> 6] = cb;
    __syncthreads();
    if (t == 0) {
        float s = 0.f;
#pragma unroll
        for (int w = 0; w < TPB / 64; w++) s += s_red[w];
        atomicAdd(out, s);
    }
}

extern "C" void kernel_launch(void* const* d_in, const int* in_sizes, int n_in,
                              void* d_out, int out_size, void* d_ws, size_t ws_size,
                              hipStream_t stream) {
    const float* preds  = (const float*)d_in[0];
    const float* labels = (const float*)d_in[1];
    float* out = (float*)d_out;
    float* ws  = (float*)d_ws;

    const size_t P = (size_t)SPLIT * BB * NN;    // 2M floats (8 MB) per array
    float* Sp  = ws;
    float* Tp  = ws + P;
    float* RSp = ws + 2 * P;
    float* RRp = ws + 3 * P;
    float* curb[2]  = {ws + 4 * P,          ws + 4 * P + BN};
    float* costb[2] = {ws + 4 * P + 2 * BN, ws + 4 * P + 3 * BN};
    // 32 MB + 512 KB; every slot written before read each call.

    hipMemsetAsync(d_out, 0, sizeof(float), stream);

    static const float efs[10] = {-16384.0f, -4096.0f, -1024.0f, -256.0f, -64.0f,
                                  -16.0f, -4.0f, -1.0f, -0.25f, 0.0f};
    const float log2e = 1.44269504088896f;
    const int grid = BB * SPLIT;   // 1024 blocks = 4/CU
    for (int k = 0; k < 10; k++) {
        float c1 = efs[k] * log2e;
        float invc1 = (efs[k] != 0.0f) ? 1.0f / c1 : 0.0f;
        passA<<<grid, TPB, 0, stream>>>(preds, labels,
            curb[(k + 1) & 1], curb[k & 1],
            RSp, RRp, Sp, Tp, out, c1, k);
        passB<<<grid, TPB, 0, stream>>>(preds, labels,
            Sp, Tp,
            costb[k & 1], costb[(k + 1) & 1],
            RSp, RRp,
            c1, invc1, k, (k == 9) ? 1 : 0);
    }
    finalK<<<BN / TPB, TPB, 0, stream>>>(curb[1], RRp, out);
}

// Round 7
// 376.696 us; speedup vs baseline: 6.9749x; 1.2625x over previous
//
#include <hip/hip_runtime.h>
#include <cstddef>

#define BB    16
#define NN    2048
#define BN    (BB * NN)
#define TPB   512
#define SPLIT 16                 // row (col) slices per batch
#define TILE  128                // NN / SPLIT rows staged per block
#define MC    2                  // column chunks per batch
#define CHUNK 1024               // cols per block = TPB * 2
#define EPSF  1e-9f

typedef float f2 __attribute__((ext_vector_type(2)));

__device__ __forceinline__ float fast_exp2(float x) {
#if __has_builtin(__builtin_amdgcn_exp2f)
    return __builtin_amdgcn_exp2f(x);
#else
    return exp2f(x);
#endif
}

// pack (x,y,z,|v|^2) float4 per point — rows (preds) and cols (labels)
__global__ void prep(const float* __restrict__ preds, const float* __restrict__ labels,
                     float4* __restrict__ Prow, float4* __restrict__ Lcol) {
    int i = blockIdx.x * 256 + threadIdx.x;
    const float* p = preds + (size_t)i * 3;
    float x = p[0], y = p[1], z = p[2];
    Prow[i] = make_float4(x, y, z, x * x + y * y + z * z);
    const float* l = labels + (size_t)i * 3;
    float a = l[0], c = l[1], d = l[2];
    Lcol[i] = make_float4(a, c, d, a * a + c * c + d * d);
}

// passA(k): fused combB(k-1) + column sums S,T of round k (atomic partials).
// Rows come from wave-uniform float4 loads (no ds_read_b128); cu via ds_read_b32.
__global__ __launch_bounds__(TPB, 4) void passA(
    const float4* __restrict__ Prow, const float4* __restrict__ Lcol,
    const float* __restrict__ curprev, float* __restrict__ curout,
    const float* __restrict__ RSp, const float* __restrict__ RRp,
    float* __restrict__ RSz, float* __restrict__ RRz,
    float* __restrict__ S, float* __restrict__ T,
    float* __restrict__ out, float c1, int k)
{
    __shared__ float s_cu[TILE];
    const int blk = blockIdx.x;
    const int split = blk & (SPLIT - 1), mc = (blk >> 4) & 1, b = blk >> 5;
    const int t = threadIdx.x;
    const int base = b * NN;
    const int row0 = split * TILE;

    if (t < TILE) {
        int idx = base + row0 + t;
        float cu, contrib = 0.f;
        if (k == 0) cu = 1.f;
        else {
            float cup = curprev[idx], rs = RSp[idx], rr = RRp[idx];
            contrib = cup * rr;                    // round k-1 result term
            cu = fmaxf(cup * (1.f - rs), 0.f);
        }
        s_cu[t] = cu;
        if (mc == 0) {
            curout[idx] = cu;
            RSz[idx] = 0.f; RRz[idx] = 0.f;        // ready for passB's atomics
        }
        if (k > 0 && mc == 0) {
#pragma unroll
            for (int o = 32; o > 0; o >>= 1) contrib += __shfl_down(contrib, o, 64);
            if ((t & 63) == 0) atomicAdd(out, contrib);   // one per wave (2/block)
        }
    }

    // register-held label columns (2 per thread), prescaled
    const int m0 = mc * CHUNK + t;                 // cols m0 and m0+TPB
    float4 L0 = Lcol[base + m0], L1 = Lcol[base + m0 + TPB];
    const float n2c1 = -2.f * c1;
    f2 gx = (f2){n2c1 * L0.x, n2c1 * L1.x};
    f2 gy = (f2){n2c1 * L0.y, n2c1 * L1.y};
    f2 gz = (f2){n2c1 * L0.z, n2c1 * L1.z};
    f2 am = (f2){c1 * L0.w, c1 * L1.w};
    f2 Sa = (f2){0.f, 0.f}, Ta = (f2){0.f, 0.f};
    __syncthreads();

    const float4* prow = Prow + base + row0;
#pragma unroll 4
    for (int j = 0; j < TILE; j++) {
        float4 P = prow[j];                        // wave-uniform address
        float cu = s_cu[j];                        // LDS broadcast (b32)
        f2 arg = P.x * gx + (P.y * gy + (P.z * gz + (am + c1 * P.w)));
        f2 e; e.x = fast_exp2(arg.x); e.y = fast_exp2(arg.y);
        Sa += e;
        Ta += e * cu;
    }
    int i0 = base + m0, i1 = base + m0 + TPB;
    atomicAdd(&S[i0], Sa.x); atomicAdd(&S[i1], Sa.y);
    atomicAdd(&T[i0], Ta.x); atomicAdd(&T[i1], Ta.y);
}

// passB(k): fused combA(k) + row sums RS,RR of round k (atomic partials).
__global__ __launch_bounds__(TPB, 4) void passB(
    const float4* __restrict__ Prow, const float4* __restrict__ Lcol,
    const float* __restrict__ S, const float* __restrict__ T,
    const float* __restrict__ costprev, float* __restrict__ costout,
    float* __restrict__ Sz, float* __restrict__ Tz,
    float* __restrict__ RS, float* __restrict__ RR,
    float c1, float invc1, int k, int last)
{
    __shared__ float s_cc[TILE];
    const int blk = blockIdx.x;
    const int split = blk & (SPLIT - 1), nc = (blk >> 4) & 1, b = blk >> 5;
    const int t = threadIdx.x;
    const int base = b * NN;
    const int col0 = split * TILE;

    if (t < TILE) {                                // combA for TILE columns
        int idx = base + col0 + t;
        float Sv = S[idx], Tv = T[idx];
        float cost = (k == 0) ? 1.f : costprev[idx];
        float D1 = fmaf(cost, Sv, EPSF);
        float S2 = cost * Tv / D1;
        float bw = fminf(cost / (S2 + EPSF), 1.f);
        s_cc[t] = cost * bw / D1;
        if (nc == 0) {
            costout[idx] = fmaxf(fmaf(-S2, bw, cost), 0.f);
            Sz[idx] = 0.f; Tz[idx] = 0.f;          // ready for next passA
        }
    }

    // register-held pred rows (2 per thread)
    const int n0 = nc * CHUNK + t;
    float4 P0 = Prow[base + n0], P1 = Prow[base + n0 + TPB];
    const float fx = last ? 1.f : -2.f * c1;
    f2 hx = (f2){fx * P0.x, fx * P1.x};
    f2 hy = (f2){fx * P0.y, fx * P1.y};
    f2 hz = (f2){fx * P0.z, fx * P1.z};
    f2 hn = last ? (f2){P0.w, P1.w} : (f2){c1 * P0.w, c1 * P1.w};
    f2 RSa = (f2){0.f, 0.f}, RRa = (f2){0.f, 0.f};
    __syncthreads();

    const float4* lcol = Lcol + base + col0;
    int i0 = base + n0, i1 = base + n0 + TPB;
    if (!last) {
#pragma unroll 4
        for (int j = 0; j < TILE; j++) {
            float4 L = lcol[j];                    // wave-uniform address
            float ccj = s_cc[j];                   // LDS broadcast
            f2 arg = L.x * hx + (L.y * hy + (L.z * hz + (hn + c1 * L.w)));
            f2 e; e.x = fast_exp2(arg.x); e.y = fast_exp2(arg.y);
            f2 w = e * ccj;
            RSa += w;
            RRa += w * arg;                        // sum w*arg; *1/c1 at store
        }
        atomicAdd(&RS[i0], RSa.x); atomicAdd(&RS[i1], RSa.y);
        atomicAdd(&RR[i0], RRa.x * invc1); atomicAdd(&RR[i1], RRa.y * invc1);
    } else {                                       // ef = 0: e == 1, raw pw
#pragma unroll 4
        for (int j = 0; j < TILE; j++) {
            float4 L = lcol[j];
            float ccj = s_cc[j];
            f2 dot = L.x * hx + (L.y * hy + L.z * hz);
            f2 pw = (hn + L.w) - 2.f * dot;
            RRa += ccj * pw;
        }
        atomicAdd(&RR[i0], RRa.x); atomicAdd(&RR[i1], RRa.y);
    }
}

// out += sum_n cur9[n] * RR9[n]
__global__ __launch_bounds__(TPB) void finalK(const float* __restrict__ cur,
                                              const float* __restrict__ RR,
                                              float* __restrict__ out)
{
    int i = blockIdx.x * TPB + threadIdx.x;
    float cb = cur[i] * RR[i];
#pragma unroll
    for (int o = 32; o > 0; o >>= 1) cb += __shfl_down(cb, o, 64);
    if ((threadIdx.x & 63) == 0) atomicAdd(out, cb);
}

extern "C" void kernel_launch(void* const* d_in, const int* in_sizes, int n_in,
                              void* d_out, int out_size, void* d_ws, size_t ws_size,
                              hipStream_t stream) {
    const float* preds  = (const float*)d_in[0];
    const float* labels = (const float*)d_in[1];
    float* out = (float*)d_out;
    float* ws  = (float*)d_ws;

    // layout: S0 T0 | S1 T1 | RS0 RR0 RS1 RR1 | cur0 cur1 cost0 cost1 | Prow Lcol
    float* S[2]     = {ws + 0 * BN, ws + 2 * BN};
    float* T[2]     = {ws + 1 * BN, ws + 3 * BN};
    float* RS[2]    = {ws + 4 * BN, ws + 6 * BN};
    float* RR[2]    = {ws + 5 * BN, ws + 7 * BN};
    float* curb[2]  = {ws + 8 * BN, ws + 9 * BN};
    float* costb[2] = {ws + 10 * BN, ws + 11 * BN};
    float4* Prow = (float4*)(ws + 12 * BN);
    float4* Lcol = Prow + BN;
    // total ~2.5 MB; every slot written before read each call.

    hipMemsetAsync(d_out, 0, sizeof(float), stream);
    hipMemsetAsync(ws, 0, (size_t)2 * BN * sizeof(float), stream);   // S[0], T[0]
    prep<<<BN / 256, 256, 0, stream>>>(preds, labels, Prow, Lcol);

    static const float efs[10] = {-16384.0f, -4096.0f, -1024.0f, -256.0f, -64.0f,
                                  -16.0f, -4.0f, -1.0f, -0.25f, 0.0f};
    const float log2e = 1.44269504088896f;
    const int grid = BB * SPLIT * MC;   // 512 blocks = 2/CU, 16 waves/CU
    for (int k = 0; k < 10; k++) {
        float c1 = efs[k] * log2e;
        float invc1 = (efs[k] != 0.0f) ? 1.0f / c1 : 0.0f;
        int pk = k & 1, pp = (k + 1) & 1;
        passA<<<grid, TPB, 0, stream>>>(Prow, Lcol,
            curb[pp], curb[pk],
            RS[pp], RR[pp],          // prev round's row sums (read)
            RS[pk], RR[pk],          // zero for this round's passB
            S[pk], T[pk],            // atomic col sums
            out, c1, k);
        passB<<<grid, TPB, 0, stream>>>(Prow, Lcol,
            S[pk], T[pk],
            costb[pk], costb[pp],
            S[pp], T[pp],            // zero for next round's passA
            RS[pk], RR[pk],
            c1, invc1, k, (k == 9) ? 1 : 0);
    }
    finalK<<<BN / TPB, TPB, 0, stream>>>(curb[1], RR[1], out);
}